// Round 18
// baseline (543.056 us; speedup 1.0000x reference)
//
#include <hip/hip_runtime.h>

// Joiner: R=32000 rows, K=512, OV=1999, V=2000.
// out  = [blank | enc@W_ev^T + b_ev + vdp]  (R x 2000)
// vdp  = log_softmax(biasnorm(vocab_dec)@W_dv^T + b_dv)  (R x 1999)

#define R_TOTAL 32000
#define OV 1999
#define WG_ROWS 2049   // 1 guard row + 1999 real + 49 zero pad

typedef __attribute__((ext_vector_type(8))) short bh8;
typedef __attribute__((ext_vector_type(4))) float fx4;

__device__ __forceinline__ unsigned short f2bf(float f) {
  union { float f; unsigned u; } v; v.f = f;
  unsigned r = v.u + 0x7fffu + ((v.u >> 16) & 1u);
  return (unsigned short)(r >> 16);
}
__device__ __forceinline__ float bf2f(unsigned short h) {
  union { unsigned u; float f; } v; v.u = ((unsigned)h) << 16;
  return v.f;
}
__device__ __forceinline__ void gload_lds16(const void* g, void* l) {
  __builtin_amdgcn_global_load_lds(
      (__attribute__((address_space(1))) void*)g,
      (__attribute__((address_space(3))) void*)l, 16, 0, 0);
}
// 16-byte store with only 4-byte alignment guarantee
__device__ __forceinline__ void st16u(float* dst, const float* src) {
  float v[4] = {src[0], src[1], src[2], src[3]};
  __builtin_memcpy((void*)dst, v, 16);
}

// ---- all four weight fp32->bf16 conversions in ONE kernel (grid-stride) ----
__global__ void wconv_all_kernel(const float* __restrict__ W_enc,
                                 const float* __restrict__ W_bdec,
                                 const float* __restrict__ W_dv,
                                 const float* __restrict__ W_ev,
                                 unsigned short* __restrict__ Wenc_b,
                                 unsigned short* __restrict__ Wbdec_b,
                                 unsigned short* __restrict__ Wdv_g,
                                 unsigned short* __restrict__ Wev_g)
{
  const long long n_small = 512 * 512;
  const long long n_big   = (long long)WG_ROWS * 512;
  const long long total   = 2 * n_small + 2 * n_big;
  for (long long i = (long long)blockIdx.x * blockDim.x + threadIdx.x; i < total;
       i += (long long)gridDim.x * blockDim.x) {
    if (i < n_small) {
      Wenc_b[i] = f2bf(W_enc[i]);
    } else if (i < 2 * n_small) {
      long long j = i - n_small;
      Wbdec_b[j] = f2bf(W_bdec[j]);
    } else if (i < 2 * n_small + n_big) {
      long long j = i - 2 * n_small;
      int row = (int)(j >> 9);
      int sr = row - 1;
      Wdv_g[j] = (sr >= 0 && sr < OV) ? f2bf(W_dv[(long long)sr * 512 + (j & 511)])
                                      : (unsigned short)0;
    } else {
      long long j = i - 2 * n_small - n_big;
      int row = (int)(j >> 9);
      int sr = row - 1;
      Wev_g[j] = (sr >= 0 && sr < OV) ? f2bf(W_ev[(long long)sr * 512 + (j & 511)])
                                      : (unsigned short)0;
    }
  }
}

// ---- merged proj: enc GEMM+BiasNorm (write enc_b, keep ve in regs), then
//      bdec GEMM+BiasNorm, then blank = relu(ve+vb).W_blank + b_blank. ----
__global__ __launch_bounds__(1024)
void proj_both_kernel(const float* __restrict__ Xe,
                      const float* __restrict__ Xb,
                      const unsigned short* __restrict__ We,
                      const unsigned short* __restrict__ Wbd,
                      const float* __restrict__ b_enc,
                      const float* __restrict__ bn_enc_bias,
                      const float* __restrict__ enc_ls,
                      const float* __restrict__ b_bdec,
                      const float* __restrict__ bn_bdec_bias,
                      const float* __restrict__ bdec_ls,
                      unsigned short* __restrict__ enc_b,
                      const float* __restrict__ W_blank,
                      const float* __restrict__ b_blank,
                      float* __restrict__ blank)
{
  __shared__ __attribute__((aligned(16))) unsigned short As[128 * 64];
  __shared__ __attribute__((aligned(16))) unsigned short Bs[512 * 64];
  __shared__ float red[8][128];
  __shared__ float scale_s[128];

  const int tid = threadIdx.x;
  const int l  = tid & 63;
  const int lq = l >> 4;
  const int lr = l & 15;
  const int w  = tid >> 6;      // 0..15
  const int wr = w >> 3;        // 0..1  (64-row slab)
  const int wc = w & 7;         // 0..7  (64-col slab)
  const int rowBase = blockIdx.x * 128;

  char* AsB = (char*)As;
  char* BsB = (char*)Bs;

  fx4 acc[4][4];
  float ve[4][4][4];

  // ================= phase 1: enc =================
#pragma unroll
  for (int m = 0; m < 4; ++m)
#pragma unroll
    for (int n = 0; n < 4; ++n)
#pragma unroll
      for (int r = 0; r < 4; ++r) acc[m][n][r] = 0.f;

  for (int kt = 0; kt < 8; ++kt) {
#pragma unroll
    for (int p = 0; p < 2; ++p) {
      int g = tid + p * 1024;
      int row = g >> 4;
      int c4  = g & 15;
      const float4 v = *(const float4*)(Xe + (long long)(rowBase + row) * 512 + kt * 64 + c4 * 4);
      ushort4 h;
      h.x = f2bf(v.x); h.y = f2bf(v.y); h.z = f2bf(v.z); h.w = f2bf(v.w);
      *(ushort4*)(AsB + row * 128 + ((c4 * 8) ^ ((row & 7) << 4))) = h;
    }
#pragma unroll
    for (int p = 0; p < 4; ++p) {
      int gb = (w * 4 + p) * 64;
      int g = gb + l;
      int row = g >> 3;
      int c8 = (g & 7) ^ (row & 7);
      gload_lds16(We + (long long)row * 512 + kt * 64 + c8 * 8, BsB + gb * 16);
    }
    __syncthreads();
#pragma unroll
    for (int kk = 0; kk < 2; ++kk) {
      const int kb = (kk * 32 + lq * 8) * 2;
      bh8 a[4];
#pragma unroll
      for (int m = 0; m < 4; ++m) {
        int row = wr * 64 + m * 16 + lr;
        a[m] = *(const bh8*)(AsB + row * 128 + (kb ^ ((row & 7) << 4)));
      }
#pragma unroll
      for (int n = 0; n < 4; ++n) {
        int brow = wc * 64 + n * 16 + lr;
        bh8 bfr = *(const bh8*)(BsB + brow * 128 + (kb ^ ((brow & 7) << 4)));
#pragma unroll
        for (int m = 0; m < 4; ++m)
          acc[m][n] = __builtin_amdgcn_mfma_f32_16x16x32_bf16(a[m], bfr, acc[m][n], 0, 0, 0);
      }
    }
    __syncthreads();
  }

  {
    const float escale = expf(enc_ls[0]);
    float bl[4], bb[4];
#pragma unroll
    for (int n = 0; n < 4; ++n) {
      int col = wc * 64 + n * 16 + lr;
      bl[n] = b_enc[col];
      bb[n] = bn_enc_bias[col];
    }
    float ps[4][4];
#pragma unroll
    for (int m = 0; m < 4; ++m)
#pragma unroll
      for (int r = 0; r < 4; ++r) ps[m][r] = 0.f;
#pragma unroll
    for (int m = 0; m < 4; ++m)
#pragma unroll
      for (int n = 0; n < 4; ++n)
#pragma unroll
        for (int r = 0; r < 4; ++r) {
          float v = acc[m][n][r] + bl[n];
          float d = v - bb[n];
          ps[m][r] += d * d;
        }
#pragma unroll
    for (int off = 1; off < 16; off <<= 1)
#pragma unroll
      for (int m = 0; m < 4; ++m)
#pragma unroll
        for (int r = 0; r < 4; ++r)
          ps[m][r] += __shfl_xor(ps[m][r], off);
    if (lr == 0) {
#pragma unroll
      for (int m = 0; m < 4; ++m)
#pragma unroll
        for (int r = 0; r < 4; ++r)
          red[wc][wr * 64 + m * 16 + lq * 4 + r] = ps[m][r];
    }
    __syncthreads();
    if (tid < 128) {
      float s = 0.f;
#pragma unroll
      for (int c = 0; c < 8; ++c) s += red[c][tid];
      scale_s[tid] = escale * rsqrtf(s * (1.0f / 512.0f));
    }
    __syncthreads();

#pragma unroll
    for (int m = 0; m < 4; ++m)
#pragma unroll
      for (int n = 0; n < 4; ++n)
#pragma unroll
        for (int r = 0; r < 4; ++r) {
          int rl = wr * 64 + m * 16 + lq * 4 + r;
          int col = wc * 64 + n * 16 + lr;
          float v = (acc[m][n][r] + bl[n]) * scale_s[rl];
          ve[m][n][r] = v;
          enc_b[(long long)(rowBase + rl) * 512 + col] = f2bf(v);
        }
  }
  __syncthreads();

  // ================= phase 2: bdec + blank =================
#pragma unroll
  for (int m = 0; m < 4; ++m)
#pragma unroll
    for (int n = 0; n < 4; ++n)
#pragma unroll
      for (int r = 0; r < 4; ++r) acc[m][n][r] = 0.f;

  for (int kt = 0; kt < 8; ++kt) {
#pragma unroll
    for (int p = 0; p < 2; ++p) {
      int g = tid + p * 1024;
      int row = g >> 4;
      int c4  = g & 15;
      const float4 v = *(const float4*)(Xb + (long long)(rowBase + row) * 512 + kt * 64 + c4 * 4);
      ushort4 h;
      h.x = f2bf(v.x); h.y = f2bf(v.y); h.z = f2bf(v.z); h.w = f2bf(v.w);
      *(ushort4*)(AsB + row * 128 + ((c4 * 8) ^ ((row & 7) << 4))) = h;
    }
#pragma unroll
    for (int p = 0; p < 4; ++p) {
      int gb = (w * 4 + p) * 64;
      int g = gb + l;
      int row = g >> 3;
      int c8 = (g & 7) ^ (row & 7);
      gload_lds16(Wbd + (long long)row * 512 + kt * 64 + c8 * 8, BsB + gb * 16);
    }
    __syncthreads();
#pragma unroll
    for (int kk = 0; kk < 2; ++kk) {
      const int kb = (kk * 32 + lq * 8) * 2;
      bh8 a[4];
#pragma unroll
      for (int m = 0; m < 4; ++m) {
        int row = wr * 64 + m * 16 + lr;
        a[m] = *(const bh8*)(AsB + row * 128 + (kb ^ ((row & 7) << 4)));
      }
#pragma unroll
      for (int n = 0; n < 4; ++n) {
        int brow = wc * 64 + n * 16 + lr;
        bh8 bfr = *(const bh8*)(BsB + brow * 128 + (kb ^ ((brow & 7) << 4)));
#pragma unroll
        for (int m = 0; m < 4; ++m)
          acc[m][n] = __builtin_amdgcn_mfma_f32_16x16x32_bf16(a[m], bfr, acc[m][n], 0, 0, 0);
      }
    }
    __syncthreads();
  }

  {
    const float escale = expf(bdec_ls[0]);
    float bl[4], bb[4], wb[4];
#pragma unroll
    for (int n = 0; n < 4; ++n) {
      int col = wc * 64 + n * 16 + lr;
      bl[n] = b_bdec[col];
      bb[n] = bn_bdec_bias[col];
      wb[n] = W_blank[col];
    }
    float ps[4][4];
#pragma unroll
    for (int m = 0; m < 4; ++m)
#pragma unroll
      for (int r = 0; r < 4; ++r) ps[m][r] = 0.f;
#pragma unroll
    for (int m = 0; m < 4; ++m)
#pragma unroll
      for (int n = 0; n < 4; ++n)
#pragma unroll
        for (int r = 0; r < 4; ++r) {
          float v = acc[m][n][r] + bl[n];
          float d = v - bb[n];
          ps[m][r] += d * d;
        }
#pragma unroll
    for (int off = 1; off < 16; off <<= 1)
#pragma unroll
      for (int m = 0; m < 4; ++m)
#pragma unroll
        for (int r = 0; r < 4; ++r)
          ps[m][r] += __shfl_xor(ps[m][r], off);
    if (lr == 0) {
#pragma unroll
      for (int m = 0; m < 4; ++m)
#pragma unroll
        for (int r = 0; r < 4; ++r)
          red[wc][wr * 64 + m * 16 + lq * 4 + r] = ps[m][r];
    }
    __syncthreads();
    if (tid < 128) {
      float s = 0.f;
#pragma unroll
      for (int c = 0; c < 8; ++c) s += red[c][tid];
      scale_s[tid] = escale * rsqrtf(s * (1.0f / 512.0f));
    }
    __syncthreads();

    float pb[4][4];
#pragma unroll
    for (int m = 0; m < 4; ++m)
#pragma unroll
      for (int r = 0; r < 4; ++r) pb[m][r] = 0.f;
#pragma unroll
    for (int m = 0; m < 4; ++m)
#pragma unroll
      for (int n = 0; n < 4; ++n)
#pragma unroll
        for (int r = 0; r < 4; ++r) {
          int rl = wr * 64 + m * 16 + lq * 4 + r;
          float v = (acc[m][n][r] + bl[n]) * scale_s[rl];
          float s = ve[m][n][r] + v;
          s = s > 0.f ? s : 0.f;
          pb[m][r] += s * wb[n];
        }
#pragma unroll
    for (int off = 1; off < 16; off <<= 1)
#pragma unroll
      for (int m = 0; m < 4; ++m)
#pragma unroll
        for (int r = 0; r < 4; ++r)
          pb[m][r] += __shfl_xor(pb[m][r], off);
    if (lr == 0) {
#pragma unroll
      for (int m = 0; m < 4; ++m)
#pragma unroll
        for (int r = 0; r < 4; ++r)
          red[wc][wr * 64 + m * 16 + lq * 4 + r] = pb[m][r];
    }
    __syncthreads();
    if (tid < 128) {
      float s = 0.f;
#pragma unroll
      for (int c = 0; c < 8; ++c) s += red[c][tid];
      blank[rowBase + tid] = s + b_blank[0];
    }
  }
}

// ---- BiasNorm of vocab_decoder_out (one wave per row) ----
__global__ __launch_bounds__(256)
void vdec_norm_kernel(const float* __restrict__ X, const float* __restrict__ bn_bias,
                      const float* __restrict__ log_scale, unsigned short* __restrict__ dst)
{
  const int l = threadIdx.x & 63;
  const long long row = (long long)blockIdx.x * 4 + (threadIdx.x >> 6);
  const float* xr = X + row * 512 + l * 8;
  float4 v0 = *(const float4*)xr;
  float4 v1 = *(const float4*)(xr + 4);
  float xv[8] = {v0.x, v0.y, v0.z, v0.w, v1.x, v1.y, v1.z, v1.w};
  const float4 b0 = *(const float4*)(bn_bias + l * 8);
  const float4 b1 = *(const float4*)(bn_bias + l * 8 + 4);
  float bv[8] = {b0.x, b0.y, b0.z, b0.w, b1.x, b1.y, b1.z, b1.w};
  float s = 0.f;
#pragma unroll
  for (int i = 0; i < 8; ++i) { float d = xv[i] - bv[i]; s += d * d; }
#pragma unroll
  for (int off = 1; off < 64; off <<= 1) s += __shfl_xor(s, off);
  const float sc = expf(log_scale[0]) * rsqrtf(s * (1.0f / 512.0f));
  bh8 o;
#pragma unroll
  for (int i = 0; i < 8; ++i) o[i] = (short)f2bf(xv[i] * sc);
  *(bh8*)(dst + row * 512 + l * 8) = o;
}

// Round-5 XCD swizzle: XCD x owns swz in [500x,500x+500) -> bx fast (streams
// row-panels), by in {2x,2x+1} -> per-XCD weight set = 2 tiles (L2-resident).
__device__ __forceinline__ void xcd_swz_250x16(int& bx, int& by) {
  int bid = blockIdx.y * 250 + blockIdx.x;
  int swz = (bid & 7) * 500 + (bid >> 3);
  bx = swz % 250;
  by = swz / 250;
}

// ---- pass A: vdec_b @ W_dv^T + b_dv -> per-(row, colblock) stats ONLY ----
// stats[cb * R_TOTAL + row] = (max, sumexp).  R5/R13-proven 256-thread form.
__global__ __launch_bounds__(256, 2)
void gemm_stats_kernel(const unsigned short* __restrict__ Abf,
                       const unsigned short* __restrict__ Wb,
                       const float* __restrict__ bias,
                       float2* __restrict__ stats)
{
  __shared__ __attribute__((aligned(16))) unsigned short As[128 * 64];
  __shared__ __attribute__((aligned(16))) unsigned short Bs[128 * 64];
  __shared__ float smax[2][128];
  __shared__ float ssum[2][128];
  const int tid = threadIdx.x;
  const int l  = tid & 63, lq = l >> 4, lr = l & 15;
  const int w  = tid >> 6;
  const int wr = w >> 1, wc = w & 1;
  int bx, by;
  xcd_swz_250x16(bx, by);
  const int rowBase = bx * 128;
  const int colBase = by * 128;
  char* AsB = (char*)As;
  char* BsB = (char*)Bs;

  fx4 acc[4][4];
#pragma unroll
  for (int m = 0; m < 4; ++m)
#pragma unroll
    for (int n = 0; n < 4; ++n)
#pragma unroll
      for (int r = 0; r < 4; ++r) acc[m][n][r] = 0.f;

  for (int kt = 0; kt < 8; ++kt) {
#pragma unroll
    for (int p = 0; p < 4; ++p) {
      int gb = (w * 4 + p) * 64;
      int g = gb + l;
      int row = g >> 3;
      int c8 = (g & 7) ^ (row & 7);
      gload_lds16(Abf + (long long)(rowBase + row) * 512 + kt * 64 + c8 * 8, AsB + gb * 16);
      gload_lds16(Wb  + (long long)(colBase + row) * 512 + kt * 64 + c8 * 8, BsB + gb * 16);
    }
    __syncthreads();
#pragma unroll
    for (int kk = 0; kk < 2; ++kk) {
      const int kb = (kk * 32 + lq * 8) * 2;
      bh8 a[4];
#pragma unroll
      for (int m = 0; m < 4; ++m) {
        int row = wr * 64 + m * 16 + lr;
        a[m] = *(const bh8*)(AsB + row * 128 + (kb ^ ((row & 7) << 4)));
      }
#pragma unroll
      for (int n = 0; n < 4; ++n) {
        int brow = wc * 64 + n * 16 + lr;
        bh8 bfr = *(const bh8*)(BsB + brow * 128 + (kb ^ ((brow & 7) << 4)));
#pragma unroll
        for (int m = 0; m < 4; ++m)
          acc[m][n] = __builtin_amdgcn_mfma_f32_16x16x32_bf16(a[m], bfr, acc[m][n], 0, 0, 0);
      }
    }
    __syncthreads();
  }

  float bl[4]; bool cv[4];
#pragma unroll
  for (int n = 0; n < 4; ++n) {
    int col = colBase + wc * 64 + n * 16 + lr;
    cv[n] = (col < OV);
    bl[n] = cv[n] ? bias[col] : 0.f;
  }

  float mloc[4][4];
#pragma unroll
  for (int m = 0; m < 4; ++m)
#pragma unroll
    for (int r = 0; r < 4; ++r) mloc[m][r] = -3.4e38f;
#pragma unroll
  for (int m = 0; m < 4; ++m)
#pragma unroll
    for (int n = 0; n < 4; ++n)
      if (cv[n])
#pragma unroll
        for (int r = 0; r < 4; ++r)
          mloc[m][r] = fmaxf(mloc[m][r], acc[m][n][r] + bl[n]);
#pragma unroll
  for (int off = 1; off < 16; off <<= 1)
#pragma unroll
    for (int m = 0; m < 4; ++m)
#pragma unroll
      for (int r = 0; r < 4; ++r)
        mloc[m][r] = fmaxf(mloc[m][r], __shfl_xor(mloc[m][r], off));
  if (lr == 0) {
#pragma unroll
    for (int m = 0; m < 4; ++m)
#pragma unroll
      for (int r = 0; r < 4; ++r)
        smax[wc][wr * 64 + m * 16 + lq * 4 + r] = mloc[m][r];
  }
  __syncthreads();
  float M[4][4];
#pragma unroll
  for (int m = 0; m < 4; ++m)
#pragma unroll
    for (int r = 0; r < 4; ++r) {
      int row = wr * 64 + m * 16 + lq * 4 + r;
      M[m][r] = fmaxf(smax[0][row], smax[1][row]);
    }
  float sl[4][4];
#pragma unroll
  for (int m = 0; m < 4; ++m)
#pragma unroll
    for (int r = 0; r < 4; ++r) sl[m][r] = 0.f;
#pragma unroll
  for (int m = 0; m < 4; ++m)
#pragma unroll
    for (int n = 0; n < 4; ++n)
      if (cv[n]) {
#pragma unroll
        for (int r = 0; r < 4; ++r) {
          float v = acc[m][n][r] + bl[n];
          sl[m][r] += __expf(v - M[m][r]);
        }
      }
#pragma unroll
  for (int off = 1; off < 16; off <<= 1)
#pragma unroll
    for (int m = 0; m < 4; ++m)
#pragma unroll
      for (int r = 0; r < 4; ++r)
        sl[m][r] += __shfl_xor(sl[m][r], off);
  if (lr == 0) {
#pragma unroll
    for (int m = 0; m < 4; ++m)
#pragma unroll
      for (int r = 0; r < 4; ++r)
        ssum[wc][wr * 64 + m * 16 + lq * 4 + r] = sl[m][r];
  }
  __syncthreads();
  if (tid < 128) {
    float2 st;
    st.x = fmaxf(smax[0][tid], smax[1][tid]);
    st.y = ssum[0][tid] + ssum[1][tid];
    stats[(long long)by * R_TOTAL + rowBase + tid] = st;
  }
}

// ---- pass B: reduce stats -> per-row logZ ----
__global__ __launch_bounds__(256)
void lz_kernel(const float2* __restrict__ stats, float* __restrict__ lz)
{
  int row = blockIdx.x * 256 + threadIdx.x;
  if (row >= R_TOTAL) return;
  float2 st[16];
  float M = -3.4e38f;
#pragma unroll
  for (int i = 0; i < 16; ++i) {
    st[i] = stats[(long long)i * R_TOTAL + row];
    M = fmaxf(M, st[i].x);
  }
  float S = 0.f;
#pragma unroll
  for (int i = 0; i < 16; ++i) S += st[i].y * __expf(st[i].x - M);
  lz[row] = M + logf(S);
}

// ---- pass C: recompute vdec logits + enc@W_ev^T; -1-shifted col blocking
//      (guarded weights). 512 threads / 8 waves (64x32 per wave) -> 4 waves/SIMD.
//      LDS-transposed epilogue with aligned stores + lq-parity flip. ----
__global__ __launch_bounds__(512, 4)
void gemm_fused_kernel(const unsigned short* __restrict__ Av_g,   // vdec_b
                       const unsigned short* __restrict__ Ae_g,   // enc_b
                       const unsigned short* __restrict__ Wdv_g,  // guarded (+1 row)
                       const unsigned short* __restrict__ Wev_g,  // guarded (+1 row)
                       const float* __restrict__ b_dv,
                       const float* __restrict__ b_ev,
                       const float* __restrict__ lz,
                       const float* __restrict__ blank,
                       float* __restrict__ vdp,
                       float* __restrict__ outp)
{
  __shared__ __attribute__((aligned(16))) unsigned short As[128 * 64];
  __shared__ __attribute__((aligned(16))) unsigned short Bs[128 * 64];
  const int tid = threadIdx.x;
  const int l  = tid & 63, lq = l >> 4, lr = l & 15;
  const int w  = tid >> 6;      // 0..7
  const int wr = w >> 2;        // 0..1 (64-row slab)
  const int wc = w & 3;         // 0..3 (32-col slab)
  int bx, by;
  xcd_swz_250x16(bx, by);
  const int rowBase = bx * 128;
  const int colBase = by * 128;   // guarded-weight row base; vocab col = colBase-1+j
  char* AsB = (char*)As;
  char* BsB = (char*)Bs;

  fx4 accV[4][2], accE[4][2];
#pragma unroll
  for (int m = 0; m < 4; ++m)
#pragma unroll
    for (int n = 0; n < 2; ++n)
#pragma unroll
      for (int r = 0; r < 4; ++r) { accV[m][n][r] = 0.f; accE[m][n][r] = 0.f; }

  // ---- phase V ----
  for (int kt = 0; kt < 8; ++kt) {
#pragma unroll
    for (int p = 0; p < 2; ++p) {
      int gb = (w * 2 + p) * 64;
      int g = gb + l;
      int row = g >> 3;
      int c8 = (g & 7) ^ (row & 7);
      gload_lds16(Av_g  + (long long)(rowBase + row) * 512 + kt * 64 + c8 * 8, AsB + gb * 16);
      gload_lds16(Wdv_g + (long long)(colBase + row) * 512 + kt * 64 + c8 * 8, BsB + gb * 16);
    }
    __syncthreads();
#pragma unroll
    for (int kk = 0; kk < 2; ++kk) {
      const int kb = (kk * 32 + lq * 8) * 2;
      bh8 a[4];
#pragma unroll
      for (int m = 0; m < 4; ++m) {
        int row = wr * 64 + m * 16 + lr;
        a[m] = *(const bh8*)(AsB + row * 128 + (kb ^ ((row & 7) << 4)));
      }
#pragma unroll
      for (int n = 0; n < 2; ++n) {
        int brow = wc * 32 + n * 16 + lr;
        bh8 bfr = *(const bh8*)(BsB + brow * 128 + (kb ^ ((brow & 7) << 4)));
#pragma unroll
        for (int m = 0; m < 4; ++m)
          accV[m][n] = __builtin_amdgcn_mfma_f32_16x16x32_bf16(a[m], bfr, accV[m][n], 0, 0, 0);
      }
    }
    __syncthreads();
  }

  // ---- phase E ----
  for (int kt = 0; kt < 8; ++kt) {
#pragma unroll
    for (int p = 0; p < 2; ++p) {
      int gb = (w * 2 + p) * 64;
      int g = gb + l;
      int row = g >> 3;
      int c8 = (g & 7) ^ (row & 7);
      gload_lds16(Ae_g  + (long long)(rowBase + row) * 512 + kt * 64 + c8 * 8, AsB + gb * 16);
      gload_lds16(Wev_g + (long long)(colBase + row) * 512 + kt * 64 + c8 * 8, BsB + gb * 16);
    }
    __syncthreads();
#pragma unroll
    for (int kk = 0; kk < 2; ++kk) {
      const int kb = (kk * 32 + lq * 8) * 2;
      bh8 a[4];
#pragma unroll
      for (int m = 0; m < 4; ++m) {
        int row = wr * 64 + m * 16 + lr;
        a[m] = *(const bh8*)(AsB + row * 128 + (kb ^ ((row & 7) << 4)));
      }
#pragma unroll
      for (int n = 0; n < 2; ++n) {
        int brow = wc * 32 + n * 16 + lr;
        bh8 bfr = *(const bh8*)(BsB + brow * 128 + (kb ^ ((brow & 7) << 4)));
#pragma unroll
        for (int m = 0; m < 4; ++m)
          accE[m][n] = __builtin_amdgcn_mfma_f32_16x16x32_bf16(a[m], bfr, accE[m][n], 0, 0, 0);
      }
    }
    __syncthreads();
  }

  float lzv[4][4];
#pragma unroll
  for (int m = 0; m < 4; ++m)
#pragma unroll
    for (int r = 0; r < 4; ++r)
      lzv[m][r] = lz[rowBase + wr * 64 + m * 16 + lq * 4 + r];

  // ---- epilogue: LDS transpose (4 chunks of 32 rows), aligned stores ----
  float* Lvd = (float*)As;   // 32 x 128 f32 = 16 KB
  float* Lov = (float*)Bs;   // 32 x 128 f32 = 16 KB

  const int c0 = (by == 0) ? 0 : (colBase - 1);
  const int j0 = (by == 0) ? 1 : 0;
  const int Lv = min(OV, colBase + 127) - c0;   // 127 / 128 / 80

  const int flipw = (lq & 1) << 4;

#pragma unroll
  for (int c = 0; c < 4; ++c) {
    __syncthreads();
    if (wr == (c >> 1)) {
#pragma unroll
      for (int mm = 0; mm < 2; ++mm) {
        const int m = (c & 1) * 2 + mm;
#pragma unroll
        for (int n = 0; n < 2; ++n) {
          int j = wc * 32 + n * 16 + lr;
          int cg = colBase - 1 + j;
          bool v = (cg >= 0 && cg < OV);
          float bdv = v ? b_dv[cg] : 0.f;
          float bev = v ? b_ev[cg] : 0.f;
          int jx = j ^ flipw;
#pragma unroll
          for (int r = 0; r < 4; ++r) {
            int lrow = 16 * mm + lq * 4 + r;
            float vd = accV[m][n][r] + bdv - lzv[m][r];
            float ov = accE[m][n][r] + bev + vd;
            if (by == 0 && j == 0) ov = blank[rowBase + 32 * c + lrow];
            Lvd[lrow * 128 + jx] = vd;
            Lov[lrow * 128 + jx] = ov;
          }
        }
      }
    }
    __syncthreads();

    // out: positions [colBase, colBase+128) of each row -- 16-float aligned
#pragma unroll
    for (int pass = 0; pass < 2; ++pass) {
      int lrow = pass * 16 + (tid >> 5);
      int lane32 = tid & 31;
      int flip = ((lrow >> 2) & 1) << 4;
      long long rg = rowBase + 32 * c + lrow;
      int p = colBase + lane32 * 4;
      if (p < 2000) {
        float4 vv = *(const float4*)&Lov[lrow * 128 + ((lane32 * 4) ^ flip)];
        *(float4*)(outp + rg * 2000 + p) = vv;
      }
    }
    // vdp: cols [c0, c0+Lv) of each row (unaligned rows; 512B bursts)
#pragma unroll
    for (int pass = 0; pass < 2; ++pass) {
      int lrow = pass * 16 + (tid >> 5);
      int lane32 = tid & 31;
      int flip = ((lrow >> 2) & 1) << 4;
      long long rg = rowBase + 32 * c + lrow;
      int k4 = lane32 * 4;
      if (k4 < Lv) {
        float* dst = vdp + rg * OV + c0 + k4;
        int rem = Lv - k4;
        if (rem >= 4 && j0 == 0) {
          float4 vv = *(const float4*)&Lvd[lrow * 128 + (k4 ^ flip)];
          float vs[4] = {vv.x, vv.y, vv.z, vv.w};
          st16u(dst, vs);
        } else if (rem >= 4) {
          float vs[4];
#pragma unroll
          for (int q = 0; q < 4; ++q) vs[q] = Lvd[lrow * 128 + ((j0 + k4 + q) ^ flip)];
          st16u(dst, vs);
        } else {
          for (int q = 0; q < rem; ++q) dst[q] = Lvd[lrow * 128 + ((j0 + k4 + q) ^ flip)];
        }
      }
    }
  }
}

extern "C" void kernel_launch(void* const* d_in, const int* in_sizes, int n_in,
                              void* d_out, int out_size, void* d_ws, size_t ws_size,
                              hipStream_t stream) {
  const float* encoder_out  = (const float*)d_in[0];
  const float* blank_dec    = (const float*)d_in[1];
  const float* vocab_dec    = (const float*)d_in[2];
  const float* W_enc        = (const float*)d_in[3];
  const float* b_enc        = (const float*)d_in[4];
  const float* bn_enc_bias  = (const float*)d_in[5];
  const float* bn_enc_ls    = (const float*)d_in[6];
  const float* W_bdec       = (const float*)d_in[7];
  const float* b_bdec       = (const float*)d_in[8];
  const float* bn_bdec_bias = (const float*)d_in[9];
  const float* bn_bdec_ls   = (const float*)d_in[10];
  const float* bn_vdec_bias = (const float*)d_in[11];
  const float* bn_vdec_ls   = (const float*)d_in[12];
  const float* W_blank      = (const float*)d_in[13];
  const float* b_blank      = (const float*)d_in[14];
  const float* W_ev         = (const float*)d_in[15];
  const float* b_ev         = (const float*)d_in[16];
  const float* W_dv         = (const float*)d_in[17];
  const float* b_dv         = (const float*)d_in[18];

  unsigned short* Wenc_b  = (unsigned short*)d_ws;                 // 512x512
  unsigned short* Wbdec_b = Wenc_b + 512 * 512;                    // 512x512
  unsigned short* Wdv_g   = Wbdec_b + 512 * 512;                   // WG_ROWS x 512 (guard row 0)
  unsigned short* Wev_g   = Wdv_g + (size_t)WG_ROWS * 512;         // WG_ROWS x 512
  unsigned short* enc_b   = Wev_g + (size_t)WG_ROWS * 512;         // R x 512
  unsigned short* vdec_b  = enc_b + (size_t)R_TOTAL * 512;         // R x 512
  float2* stats = (float2*)(vdec_b + (size_t)R_TOTAL * 512);       // 16 x R
  float*  lzbuf = (float*)(stats + (size_t)R_TOTAL * 16);          // R
  float*  blank = lzbuf + R_TOTAL;                                 // R

  float* outp = (float*)d_out;                  // R x 2000
  float* vdp  = outp + (size_t)R_TOTAL * 2000;  // R x 1999

  wconv_all_kernel<<<1024, 256, 0, stream>>>(W_enc, W_bdec, W_dv, W_ev,
                                             Wenc_b, Wbdec_b, Wdv_g, Wev_g);

  vdec_norm_kernel<<<8000, 256, 0, stream>>>(vocab_dec, bn_vdec_bias, bn_vdec_ls, vdec_b);
  gemm_stats_kernel<<<dim3(250, 16), 256, 0, stream>>>(vdec_b, Wdv_g + 512, b_dv, stats);
  lz_kernel<<<125, 256, 0, stream>>>(stats, lzbuf);

  proj_both_kernel<<<250, 1024, 0, stream>>>(encoder_out, blank_dec, Wenc_b, Wbdec_b,
                                             b_enc, bn_enc_bias, bn_enc_ls,
                                             b_bdec, bn_bdec_bias, bn_bdec_ls,
                                             enc_b, W_blank, b_blank, blank);

  gemm_fused_kernel<<<dim3(250, 16), 512, 0, stream>>>(vdec_b, enc_b, Wdv_g, Wev_g,
                                                       b_dv, b_ev, lzbuf, blank, vdp, outp);
}

// Round 19
// 511.296 us; speedup vs baseline: 1.0621x; 1.0621x over previous
//
#include <hip/hip_runtime.h>

// Joiner: R=32000 rows, K=512, OV=1999, V=2000.
// out  = [blank | enc@W_ev^T + b_ev + vdp]  (R x 2000)
// vdp  = log_softmax(biasnorm(vocab_dec)@W_dv^T + b_dv)  (R x 1999)

#define R_TOTAL 32000
#define OV 1999
#define WG_ROWS 2049   // 1 guard row + 1999 real + 49 zero pad

typedef __attribute__((ext_vector_type(8))) short bh8;
typedef __attribute__((ext_vector_type(4))) float fx4;

__device__ __forceinline__ unsigned short f2bf(float f) {
  union { float f; unsigned u; } v; v.f = f;
  unsigned r = v.u + 0x7fffu + ((v.u >> 16) & 1u);
  return (unsigned short)(r >> 16);
}
__device__ __forceinline__ float bf2f(unsigned short h) {
  union { unsigned u; float f; } v; v.u = ((unsigned)h) << 16;
  return v.f;
}
__device__ __forceinline__ void gload_lds16(const void* g, void* l) {
  __builtin_amdgcn_global_load_lds(
      (__attribute__((address_space(1))) void*)g,
      (__attribute__((address_space(3))) void*)l, 16, 0, 0);
}
// 16-byte store with only 4-byte alignment guarantee
__device__ __forceinline__ void st16u(float* dst, const float* src) {
  float v[4] = {src[0], src[1], src[2], src[3]};
  __builtin_memcpy((void*)dst, v, 16);
}

// ---- all four weight fp32->bf16 conversions in ONE kernel (grid-stride) ----
// seg 0: Wenc (512x512, no shift)   seg 1: Wbdec (512x512, no shift)
// seg 2: Wdv_g (2049x512, shift 1)  seg 3: Wev_g (2049x512, shift 1)
__global__ void wconv_all_kernel(const float* __restrict__ W_enc,
                                 const float* __restrict__ W_bdec,
                                 const float* __restrict__ W_dv,
                                 const float* __restrict__ W_ev,
                                 unsigned short* __restrict__ Wenc_b,
                                 unsigned short* __restrict__ Wbdec_b,
                                 unsigned short* __restrict__ Wdv_g,
                                 unsigned short* __restrict__ Wev_g)
{
  const long long n_small = 512 * 512;
  const long long n_big   = (long long)WG_ROWS * 512;
  const long long total   = 2 * n_small + 2 * n_big;
  for (long long i = (long long)blockIdx.x * blockDim.x + threadIdx.x; i < total;
       i += (long long)gridDim.x * blockDim.x) {
    if (i < n_small) {
      Wenc_b[i] = f2bf(W_enc[i]);
    } else if (i < 2 * n_small) {
      long long j = i - n_small;
      Wbdec_b[j] = f2bf(W_bdec[j]);
    } else if (i < 2 * n_small + n_big) {
      long long j = i - 2 * n_small;
      int row = (int)(j >> 9);
      int sr = row - 1;
      Wdv_g[j] = (sr >= 0 && sr < OV) ? f2bf(W_dv[(long long)sr * 512 + (j & 511)])
                                      : (unsigned short)0;
    } else {
      long long j = i - 2 * n_small - n_big;
      int row = (int)(j >> 9);
      int sr = row - 1;
      Wev_g[j] = (sr >= 0 && sr < OV) ? f2bf(W_ev[(long long)sr * 512 + (j & 511)])
                                      : (unsigned short)0;
    }
  }
}

// ---- GEMM (128 rows x full N=512) + BiasNorm epilogue, 1024 threads / 16 waves ----
// MODE 0: store biasnorm result as bf16 to enc_b
// MODE 1: compute biasnorm(bdec), blank = relu(enc+bdec).W_blank + b_blank -> blank[r]
template<int MODE>
__global__ __launch_bounds__(1024)
void proj_norm_kernel(const float* __restrict__ X,
                      const unsigned short* __restrict__ Wb,
                      const float* __restrict__ b_lin,
                      const float* __restrict__ bn_bias,
                      const float* __restrict__ log_scale,
                      unsigned short* __restrict__ enc_b,
                      const float* __restrict__ W_blank,
                      const float* __restrict__ b_blank,
                      float* __restrict__ blank)
{
  __shared__ __attribute__((aligned(16))) unsigned short As[128 * 64];
  __shared__ __attribute__((aligned(16))) unsigned short Bs[512 * 64];
  __shared__ float red[8][128];
  __shared__ float scale_s[128];

  const int tid = threadIdx.x;
  const int l  = tid & 63;
  const int lq = l >> 4;
  const int lr = l & 15;
  const int w  = tid >> 6;      // 0..15
  const int wr = w >> 3;        // 0..1  (64-row slab)
  const int wc = w & 7;         // 0..7  (64-col slab)
  const int rowBase = blockIdx.x * 128;

  char* AsB = (char*)As;
  char* BsB = (char*)Bs;

  fx4 acc[4][4];
#pragma unroll
  for (int m = 0; m < 4; ++m)
#pragma unroll
    for (int n = 0; n < 4; ++n)
#pragma unroll
      for (int r = 0; r < 4; ++r) acc[m][n][r] = 0.f;

  for (int kt = 0; kt < 8; ++kt) {
#pragma unroll
    for (int p = 0; p < 2; ++p) {
      int g = tid + p * 1024;
      int row = g >> 4;
      int c4  = g & 15;
      const float4 v = *(const float4*)(X + (long long)(rowBase + row) * 512 + kt * 64 + c4 * 4);
      ushort4 h;
      h.x = f2bf(v.x); h.y = f2bf(v.y); h.z = f2bf(v.z); h.w = f2bf(v.w);
      *(ushort4*)(AsB + row * 128 + ((c4 * 8) ^ ((row & 7) << 4))) = h;
    }
#pragma unroll
    for (int p = 0; p < 4; ++p) {
      int gb = (w * 4 + p) * 64;
      int g = gb + l;
      int row = g >> 3;
      int c8 = (g & 7) ^ (row & 7);
      gload_lds16(Wb + (long long)row * 512 + kt * 64 + c8 * 8, BsB + gb * 16);
    }
    __syncthreads();

#pragma unroll
    for (int kk = 0; kk < 2; ++kk) {
      const int kb = (kk * 32 + lq * 8) * 2;
      bh8 a[4];
#pragma unroll
      for (int m = 0; m < 4; ++m) {
        int row = wr * 64 + m * 16 + lr;
        a[m] = *(const bh8*)(AsB + row * 128 + (kb ^ ((row & 7) << 4)));
      }
#pragma unroll
      for (int n = 0; n < 4; ++n) {
        int brow = wc * 64 + n * 16 + lr;
        bh8 bfr = *(const bh8*)(BsB + brow * 128 + (kb ^ ((brow & 7) << 4)));
#pragma unroll
        for (int m = 0; m < 4; ++m)
          acc[m][n] = __builtin_amdgcn_mfma_f32_16x16x32_bf16(a[m], bfr, acc[m][n], 0, 0, 0);
      }
    }
    __syncthreads();
  }

  const float escale = expf(log_scale[0]);
  float bl[4], bb[4], wb[4];
#pragma unroll
  for (int n = 0; n < 4; ++n) {
    int col = wc * 64 + n * 16 + lr;
    bl[n] = b_lin[col];
    bb[n] = bn_bias[col];
    if (MODE == 1) wb[n] = W_blank[col];
  }

  float ps[4][4];
#pragma unroll
  for (int m = 0; m < 4; ++m)
#pragma unroll
    for (int r = 0; r < 4; ++r) ps[m][r] = 0.f;
#pragma unroll
  for (int m = 0; m < 4; ++m)
#pragma unroll
    for (int n = 0; n < 4; ++n)
#pragma unroll
      for (int r = 0; r < 4; ++r) {
        float v = acc[m][n][r] + bl[n];
        float d = v - bb[n];
        ps[m][r] += d * d;
      }
#pragma unroll
  for (int off = 1; off < 16; off <<= 1)
#pragma unroll
    for (int m = 0; m < 4; ++m)
#pragma unroll
      for (int r = 0; r < 4; ++r)
        ps[m][r] += __shfl_xor(ps[m][r], off);

  if (lr == 0) {
#pragma unroll
    for (int m = 0; m < 4; ++m)
#pragma unroll
      for (int r = 0; r < 4; ++r)
        red[wc][wr * 64 + m * 16 + lq * 4 + r] = ps[m][r];
  }
  __syncthreads();
  if (tid < 128) {
    float s = 0.f;
#pragma unroll
    for (int c = 0; c < 8; ++c) s += red[c][tid];
    scale_s[tid] = escale * rsqrtf(s * (1.0f / 512.0f));
  }
  __syncthreads();

  if (MODE == 0) {
#pragma unroll
    for (int m = 0; m < 4; ++m)
#pragma unroll
      for (int n = 0; n < 4; ++n)
#pragma unroll
        for (int r = 0; r < 4; ++r) {
          int rl = wr * 64 + m * 16 + lq * 4 + r;
          int col = wc * 64 + n * 16 + lr;
          float v = (acc[m][n][r] + bl[n]) * scale_s[rl];
          enc_b[(long long)(rowBase + rl) * 512 + col] = f2bf(v);
        }
  } else {
    float pb[4][4];
#pragma unroll
    for (int m = 0; m < 4; ++m)
#pragma unroll
      for (int r = 0; r < 4; ++r) pb[m][r] = 0.f;
#pragma unroll
    for (int m = 0; m < 4; ++m)
#pragma unroll
      for (int n = 0; n < 4; ++n)
#pragma unroll
        for (int r = 0; r < 4; ++r) {
          int rl = wr * 64 + m * 16 + lq * 4 + r;
          int col = wc * 64 + n * 16 + lr;
          float v = (acc[m][n][r] + bl[n]) * scale_s[rl];
          float e = bf2f(enc_b[(long long)(rowBase + rl) * 512 + col]);
          float s = e + v;
          s = s > 0.f ? s : 0.f;
          pb[m][r] += s * wb[n];
        }
#pragma unroll
    for (int off = 1; off < 16; off <<= 1)
#pragma unroll
      for (int m = 0; m < 4; ++m)
#pragma unroll
        for (int r = 0; r < 4; ++r)
          pb[m][r] += __shfl_xor(pb[m][r], off);
    if (lr == 0) {
#pragma unroll
      for (int m = 0; m < 4; ++m)
#pragma unroll
        for (int r = 0; r < 4; ++r)
          red[wc][wr * 64 + m * 16 + lq * 4 + r] = pb[m][r];
    }
    __syncthreads();
    if (tid < 128) {
      float s = 0.f;
#pragma unroll
      for (int c = 0; c < 8; ++c) s += red[c][tid];
      blank[rowBase + tid] = s + b_blank[0];
    }
  }
}

// ---- BiasNorm of vocab_decoder_out (one wave per row) ----
__global__ __launch_bounds__(256)
void vdec_norm_kernel(const float* __restrict__ X, const float* __restrict__ bn_bias,
                      const float* __restrict__ log_scale, unsigned short* __restrict__ dst)
{
  const int l = threadIdx.x & 63;
  const long long row = (long long)blockIdx.x * 4 + (threadIdx.x >> 6);
  const float* xr = X + row * 512 + l * 8;
  float4 v0 = *(const float4*)xr;
  float4 v1 = *(const float4*)(xr + 4);
  float xv[8] = {v0.x, v0.y, v0.z, v0.w, v1.x, v1.y, v1.z, v1.w};
  const float4 b0 = *(const float4*)(bn_bias + l * 8);
  const float4 b1 = *(const float4*)(bn_bias + l * 8 + 4);
  float bv[8] = {b0.x, b0.y, b0.z, b0.w, b1.x, b1.y, b1.z, b1.w};
  float s = 0.f;
#pragma unroll
  for (int i = 0; i < 8; ++i) { float d = xv[i] - bv[i]; s += d * d; }
#pragma unroll
  for (int off = 1; off < 64; off <<= 1) s += __shfl_xor(s, off);
  const float sc = expf(log_scale[0]) * rsqrtf(s * (1.0f / 512.0f));
  bh8 o;
#pragma unroll
  for (int i = 0; i < 8; ++i) o[i] = (short)f2bf(xv[i] * sc);
  *(bh8*)(dst + row * 512 + l * 8) = o;
}

// Round-5 XCD swizzle: XCD x owns swz in [500x,500x+500) -> bx fast (streams
// row-panels), by in {2x,2x+1} -> per-XCD weight set = 2 tiles (L2-resident).
__device__ __forceinline__ void xcd_swz_250x16(int& bx, int& by) {
  int bid = blockIdx.y * 250 + blockIdx.x;
  int swz = (bid & 7) * 500 + (bid >> 3);
  bx = swz % 250;
  by = swz / 250;
}

// ---- pass A: vdec_b @ W_dv^T + b_dv -> per-(row, colblock) stats ONLY ----
// stats[cb * R_TOTAL + row] = (max, sumexp).  R5/R13-proven 256-thread form.
__global__ __launch_bounds__(256, 2)
void gemm_stats_kernel(const unsigned short* __restrict__ Abf,
                       const unsigned short* __restrict__ Wb,
                       const float* __restrict__ bias,
                       float2* __restrict__ stats)
{
  __shared__ __attribute__((aligned(16))) unsigned short As[128 * 64];
  __shared__ __attribute__((aligned(16))) unsigned short Bs[128 * 64];
  __shared__ float smax[2][128];
  __shared__ float ssum[2][128];
  const int tid = threadIdx.x;
  const int l  = tid & 63, lq = l >> 4, lr = l & 15;
  const int w  = tid >> 6;
  const int wr = w >> 1, wc = w & 1;
  int bx, by;
  xcd_swz_250x16(bx, by);
  const int rowBase = bx * 128;
  const int colBase = by * 128;
  char* AsB = (char*)As;
  char* BsB = (char*)Bs;

  fx4 acc[4][4];
#pragma unroll
  for (int m = 0; m < 4; ++m)
#pragma unroll
    for (int n = 0; n < 4; ++n)
#pragma unroll
      for (int r = 0; r < 4; ++r) acc[m][n][r] = 0.f;

  for (int kt = 0; kt < 8; ++kt) {
#pragma unroll
    for (int p = 0; p < 4; ++p) {
      int gb = (w * 4 + p) * 64;
      int g = gb + l;
      int row = g >> 3;
      int c8 = (g & 7) ^ (row & 7);
      gload_lds16(Abf + (long long)(rowBase + row) * 512 + kt * 64 + c8 * 8, AsB + gb * 16);
      gload_lds16(Wb  + (long long)(colBase + row) * 512 + kt * 64 + c8 * 8, BsB + gb * 16);
    }
    __syncthreads();
#pragma unroll
    for (int kk = 0; kk < 2; ++kk) {
      const int kb = (kk * 32 + lq * 8) * 2;
      bh8 a[4];
#pragma unroll
      for (int m = 0; m < 4; ++m) {
        int row = wr * 64 + m * 16 + lr;
        a[m] = *(const bh8*)(AsB + row * 128 + (kb ^ ((row & 7) << 4)));
      }
#pragma unroll
      for (int n = 0; n < 4; ++n) {
        int brow = wc * 64 + n * 16 + lr;
        bh8 bfr = *(const bh8*)(BsB + brow * 128 + (kb ^ ((brow & 7) << 4)));
#pragma unroll
        for (int m = 0; m < 4; ++m)
          acc[m][n] = __builtin_amdgcn_mfma_f32_16x16x32_bf16(a[m], bfr, acc[m][n], 0, 0, 0);
      }
    }
    __syncthreads();
  }

  float bl[4]; bool cv[4];
#pragma unroll
  for (int n = 0; n < 4; ++n) {
    int col = colBase + wc * 64 + n * 16 + lr;
    cv[n] = (col < OV);
    bl[n] = cv[n] ? bias[col] : 0.f;
  }

  float mloc[4][4];
#pragma unroll
  for (int m = 0; m < 4; ++m)
#pragma unroll
    for (int r = 0; r < 4; ++r) mloc[m][r] = -3.4e38f;
#pragma unroll
  for (int m = 0; m < 4; ++m)
#pragma unroll
    for (int n = 0; n < 4; ++n)
      if (cv[n])
#pragma unroll
        for (int r = 0; r < 4; ++r)
          mloc[m][r] = fmaxf(mloc[m][r], acc[m][n][r] + bl[n]);
#pragma unroll
  for (int off = 1; off < 16; off <<= 1)
#pragma unroll
    for (int m = 0; m < 4; ++m)
#pragma unroll
      for (int r = 0; r < 4; ++r)
        mloc[m][r] = fmaxf(mloc[m][r], __shfl_xor(mloc[m][r], off));
  if (lr == 0) {
#pragma unroll
    for (int m = 0; m < 4; ++m)
#pragma unroll
      for (int r = 0; r < 4; ++r)
        smax[wc][wr * 64 + m * 16 + lq * 4 + r] = mloc[m][r];
  }
  __syncthreads();
  float M[4][4];
#pragma unroll
  for (int m = 0; m < 4; ++m)
#pragma unroll
    for (int r = 0; r < 4; ++r) {
      int row = wr * 64 + m * 16 + lq * 4 + r;
      M[m][r] = fmaxf(smax[0][row], smax[1][row]);
    }
  float sl[4][4];
#pragma unroll
  for (int m = 0; m < 4; ++m)
#pragma unroll
    for (int r = 0; r < 4; ++r) sl[m][r] = 0.f;
#pragma unroll
  for (int m = 0; m < 4; ++m)
#pragma unroll
    for (int n = 0; n < 4; ++n)
      if (cv[n]) {
#pragma unroll
        for (int r = 0; r < 4; ++r) {
          float v = acc[m][n][r] + bl[n];
          sl[m][r] += __expf(v - M[m][r]);
        }
      }
#pragma unroll
  for (int off = 1; off < 16; off <<= 1)
#pragma unroll
    for (int m = 0; m < 4; ++m)
#pragma unroll
      for (int r = 0; r < 4; ++r)
        sl[m][r] += __shfl_xor(sl[m][r], off);
  if (lr == 0) {
#pragma unroll
    for (int m = 0; m < 4; ++m)
#pragma unroll
      for (int r = 0; r < 4; ++r)
        ssum[wc][wr * 64 + m * 16 + lq * 4 + r] = sl[m][r];
  }
  __syncthreads();
  if (tid < 128) {
    float2 st;
    st.x = fmaxf(smax[0][tid], smax[1][tid]);
    st.y = ssum[0][tid] + ssum[1][tid];
    stats[(long long)by * R_TOTAL + rowBase + tid] = st;
  }
}

// ---- pass B: reduce stats -> per-row logZ ----
__global__ __launch_bounds__(256)
void lz_kernel(const float2* __restrict__ stats, float* __restrict__ lz)
{
  int row = blockIdx.x * 256 + threadIdx.x;
  if (row >= R_TOTAL) return;
  float2 st[16];
  float M = -3.4e38f;
#pragma unroll
  for (int i = 0; i < 16; ++i) {
    st[i] = stats[(long long)i * R_TOTAL + row];
    M = fmaxf(M, st[i].x);
  }
  float S = 0.f;
#pragma unroll
  for (int i = 0; i < 16; ++i) S += st[i].y * __expf(st[i].x - M);
  lz[row] = M + logf(S);
}

// ---- pass C: recompute vdec logits + enc@W_ev^T; -1-shifted col blocking
//      (guarded weights). 512 threads / 8 waves (64x32 per wave) -> 4 waves/SIMD.
//      LDS-transposed epilogue with aligned stores + lq-parity flip. ----
__global__ __launch_bounds__(512, 4)
void gemm_fused_kernel(const unsigned short* __restrict__ Av_g,   // vdec_b
                       const unsigned short* __restrict__ Ae_g,   // enc_b
                       const unsigned short* __restrict__ Wdv_g,  // guarded (+1 row)
                       const unsigned short* __restrict__ Wev_g,  // guarded (+1 row)
                       const float* __restrict__ b_dv,
                       const float* __restrict__ b_ev,
                       const float* __restrict__ lz,
                       const float* __restrict__ blank,
                       float* __restrict__ vdp,
                       float* __restrict__ outp)
{
  __shared__ __attribute__((aligned(16))) unsigned short As[128 * 64];
  __shared__ __attribute__((aligned(16))) unsigned short Bs[128 * 64];
  const int tid = threadIdx.x;
  const int l  = tid & 63, lq = l >> 4, lr = l & 15;
  const int w  = tid >> 6;      // 0..7
  const int wr = w >> 2;        // 0..1 (64-row slab)
  const int wc = w & 3;         // 0..3 (32-col slab)
  int bx, by;
  xcd_swz_250x16(bx, by);
  const int rowBase = bx * 128;
  const int colBase = by * 128;   // guarded-weight row base; vocab col = colBase-1+j
  char* AsB = (char*)As;
  char* BsB = (char*)Bs;

  fx4 accV[4][2], accE[4][2];
#pragma unroll
  for (int m = 0; m < 4; ++m)
#pragma unroll
    for (int n = 0; n < 2; ++n)
#pragma unroll
      for (int r = 0; r < 4; ++r) { accV[m][n][r] = 0.f; accE[m][n][r] = 0.f; }

  // ---- phase V ----
  for (int kt = 0; kt < 8; ++kt) {
#pragma unroll
    for (int p = 0; p < 2; ++p) {
      int gb = (w * 2 + p) * 64;
      int g = gb + l;
      int row = g >> 3;
      int c8 = (g & 7) ^ (row & 7);
      gload_lds16(Av_g  + (long long)(rowBase + row) * 512 + kt * 64 + c8 * 8, AsB + gb * 16);
      gload_lds16(Wdv_g + (long long)(colBase + row) * 512 + kt * 64 + c8 * 8, BsB + gb * 16);
    }
    __syncthreads();
#pragma unroll
    for (int kk = 0; kk < 2; ++kk) {
      const int kb = (kk * 32 + lq * 8) * 2;
      bh8 a[4];
#pragma unroll
      for (int m = 0; m < 4; ++m) {
        int row = wr * 64 + m * 16 + lr;
        a[m] = *(const bh8*)(AsB + row * 128 + (kb ^ ((row & 7) << 4)));
      }
#pragma unroll
      for (int n = 0; n < 2; ++n) {
        int brow = wc * 32 + n * 16 + lr;
        bh8 bfr = *(const bh8*)(BsB + brow * 128 + (kb ^ ((brow & 7) << 4)));
#pragma unroll
        for (int m = 0; m < 4; ++m)
          accV[m][n] = __builtin_amdgcn_mfma_f32_16x16x32_bf16(a[m], bfr, accV[m][n], 0, 0, 0);
      }
    }
    __syncthreads();
  }

  // ---- phase E ----
  for (int kt = 0; kt < 8; ++kt) {
#pragma unroll
    for (int p = 0; p < 2; ++p) {
      int gb = (w * 2 + p) * 64;
      int g = gb + l;
      int row = g >> 3;
      int c8 = (g & 7) ^ (row & 7);
      gload_lds16(Ae_g  + (long long)(rowBase + row) * 512 + kt * 64 + c8 * 8, AsB + gb * 16);
      gload_lds16(Wev_g + (long long)(colBase + row) * 512 + kt * 64 + c8 * 8, BsB + gb * 16);
    }
    __syncthreads();
#pragma unroll
    for (int kk = 0; kk < 2; ++kk) {
      const int kb = (kk * 32 + lq * 8) * 2;
      bh8 a[4];
#pragma unroll
      for (int m = 0; m < 4; ++m) {
        int row = wr * 64 + m * 16 + lr;
        a[m] = *(const bh8*)(AsB + row * 128 + (kb ^ ((row & 7) << 4)));
      }
#pragma unroll
      for (int n = 0; n < 2; ++n) {
        int brow = wc * 32 + n * 16 + lr;
        bh8 bfr = *(const bh8*)(BsB + brow * 128 + (kb ^ ((brow & 7) << 4)));
#pragma unroll
        for (int m = 0; m < 4; ++m)
          accE[m][n] = __builtin_amdgcn_mfma_f32_16x16x32_bf16(a[m], bfr, accE[m][n], 0, 0, 0);
      }
    }
    __syncthreads();
  }

  float lzv[4][4];
#pragma unroll
  for (int m = 0; m < 4; ++m)
#pragma unroll
    for (int r = 0; r < 4; ++r)
      lzv[m][r] = lz[rowBase + wr * 64 + m * 16 + lq * 4 + r];

  // ---- epilogue: LDS transpose (4 chunks of 32 rows), aligned stores ----
  float* Lvd = (float*)As;   // 32 x 128 f32 = 16 KB
  float* Lov = (float*)Bs;   // 32 x 128 f32 = 16 KB

  const int c0 = (by == 0) ? 0 : (colBase - 1);
  const int j0 = (by == 0) ? 1 : 0;
  const int Lv = min(OV, colBase + 127) - c0;   // 127 / 128 / 80

  const int flipw = (lq & 1) << 4;

#pragma unroll
  for (int c = 0; c < 4; ++c) {
    __syncthreads();
    if (wr == (c >> 1)) {
#pragma unroll
      for (int mm = 0; mm < 2; ++mm) {
        const int m = (c & 1) * 2 + mm;
#pragma unroll
        for (int n = 0; n < 2; ++n) {
          int j = wc * 32 + n * 16 + lr;
          int cg = colBase - 1 + j;
          bool v = (cg >= 0 && cg < OV);
          float bdv = v ? b_dv[cg] : 0.f;
          float bev = v ? b_ev[cg] : 0.f;
          int jx = j ^ flipw;
#pragma unroll
          for (int r = 0; r < 4; ++r) {
            int lrow = 16 * mm + lq * 4 + r;
            float vd = accV[m][n][r] + bdv - lzv[m][r];
            float ov = accE[m][n][r] + bev + vd;
            if (by == 0 && j == 0) ov = blank[rowBase + 32 * c + lrow];
            Lvd[lrow * 128 + jx] = vd;
            Lov[lrow * 128 + jx] = ov;
          }
        }
      }
    }
    __syncthreads();

    // out: positions [colBase, colBase+128) of each row -- 16-float aligned
#pragma unroll
    for (int pass = 0; pass < 2; ++pass) {
      int lrow = pass * 16 + (tid >> 5);
      int lane32 = tid & 31;
      int flip = ((lrow >> 2) & 1) << 4;
      long long rg = rowBase + 32 * c + lrow;
      int p = colBase + lane32 * 4;
      if (p < 2000) {
        float4 vv = *(const float4*)&Lov[lrow * 128 + ((lane32 * 4) ^ flip)];
        *(float4*)(outp + rg * 2000 + p) = vv;
      }
    }
    // vdp: cols [c0, c0+Lv) of each row (unaligned rows; 512B bursts)
#pragma unroll
    for (int pass = 0; pass < 2; ++pass) {
      int lrow = pass * 16 + (tid >> 5);
      int lane32 = tid & 31;
      int flip = ((lrow >> 2) & 1) << 4;
      long long rg = rowBase + 32 * c + lrow;
      int k4 = lane32 * 4;
      if (k4 < Lv) {
        float* dst = vdp + rg * OV + c0 + k4;
        int rem = Lv - k4;
        if (rem >= 4 && j0 == 0) {
          float4 vv = *(const float4*)&Lvd[lrow * 128 + (k4 ^ flip)];
          float vs[4] = {vv.x, vv.y, vv.z, vv.w};
          st16u(dst, vs);
        } else if (rem >= 4) {
          float vs[4];
#pragma unroll
          for (int q = 0; q < 4; ++q) vs[q] = Lvd[lrow * 128 + ((j0 + k4 + q) ^ flip)];
          st16u(dst, vs);
        } else {
          for (int q = 0; q < rem; ++q) dst[q] = Lvd[lrow * 128 + ((j0 + k4 + q) ^ flip)];
        }
      }
    }
  }
}

extern "C" void kernel_launch(void* const* d_in, const int* in_sizes, int n_in,
                              void* d_out, int out_size, void* d_ws, size_t ws_size,
                              hipStream_t stream) {
  const float* encoder_out  = (const float*)d_in[0];
  const float* blank_dec    = (const float*)d_in[1];
  const float* vocab_dec    = (const float*)d_in[2];
  const float* W_enc        = (const float*)d_in[3];
  const float* b_enc        = (const float*)d_in[4];
  const float* bn_enc_bias  = (const float*)d_in[5];
  const float* bn_enc_ls    = (const float*)d_in[6];
  const float* W_bdec       = (const float*)d_in[7];
  const float* b_bdec       = (const float*)d_in[8];
  const float* bn_bdec_bias = (const float*)d_in[9];
  const float* bn_bdec_ls   = (const float*)d_in[10];
  const float* bn_vdec_bias = (const float*)d_in[11];
  const float* bn_vdec_ls   = (const float*)d_in[12];
  const float* W_blank      = (const float*)d_in[13];
  const float* b_blank      = (const float*)d_in[14];
  const float* W_ev         = (const float*)d_in[15];
  const float* b_ev         = (const float*)d_in[16];
  const float* W_dv         = (const float*)d_in[17];
  const float* b_dv         = (const float*)d_in[18];

  unsigned short* Wenc_b  = (unsigned short*)d_ws;                 // 512x512
  unsigned short* Wbdec_b = Wenc_b + 512 * 512;                    // 512x512
  unsigned short* Wdv_g   = Wbdec_b + 512 * 512;                   // WG_ROWS x 512 (guard row 0)
  unsigned short* Wev_g   = Wdv_g + (size_t)WG_ROWS * 512;         // WG_ROWS x 512
  unsigned short* enc_b   = Wev_g + (size_t)WG_ROWS * 512;         // R x 512
  unsigned short* vdec_b  = enc_b + (size_t)R_TOTAL * 512;         // R x 512
  float2* stats = (float2*)(vdec_b + (size_t)R_TOTAL * 512);       // 16 x R
  float*  lzbuf = (float*)(stats + (size_t)R_TOTAL * 16);          // R
  float*  blank = lzbuf + R_TOTAL;                                 // R

  float* outp = (float*)d_out;                  // R x 2000
  float* vdp  = outp + (size_t)R_TOTAL * 2000;  // R x 1999

  wconv_all_kernel<<<1024, 256, 0, stream>>>(W_enc, W_bdec, W_dv, W_ev,
                                             Wenc_b, Wbdec_b, Wdv_g, Wev_g);

  vdec_norm_kernel<<<8000, 256, 0, stream>>>(vocab_dec, bn_vdec_bias, bn_vdec_ls, vdec_b);
  gemm_stats_kernel<<<dim3(250, 16), 256, 0, stream>>>(vdec_b, Wdv_g + 512, b_dv, stats);
  lz_kernel<<<125, 256, 0, stream>>>(stats, lzbuf);

  proj_norm_kernel<0><<<250, 1024, 0, stream>>>(encoder_out, Wenc_b, b_enc, bn_enc_bias,
                                                bn_enc_ls, enc_b, nullptr, nullptr, nullptr);
  proj_norm_kernel<1><<<250, 1024, 0, stream>>>(blank_dec, Wbdec_b, b_bdec, bn_bdec_bias,
                                                bn_bdec_ls, enc_b, W_blank, b_blank, blank);

  gemm_fused_kernel<<<dim3(250, 16), 512, 0, stream>>>(vdec_b, enc_b, Wdv_g, Wev_g,
                                                       b_dv, b_ev, lzbuf, blank, vdp, outp);
}